// Round 4
// baseline (545.998 us; speedup 1.0000x reference)
//
#include <hip/hip_runtime.h>
#include <stdint.h>

#define NTOK 16384
#define DIM 2048
#define HIDDEN 1408
#define NEXP 8
#define NPRIME 2816   // 2*HIDDEN, 16-col interleaved w1/w3

typedef short short8 __attribute__((ext_vector_type(8)));
typedef float f32x4 __attribute__((ext_vector_type(4)));
typedef unsigned short u16;

// round-to-nearest-even fp32 -> bf16
__device__ __forceinline__ u16 f2bf(float f) {
    uint32_t u = __float_as_uint(f);
    return (u16)((u + 0x7fffu + ((u >> 16) & 1u)) >> 16);
}

// async global->LDS, 16B per lane (LDS dest = wave-uniform base + lane*16)
__device__ __forceinline__ void gload16(const u16* g, u16* l) {
    __builtin_amdgcn_global_load_lds(
        (const __attribute__((address_space(1))) void*)g,
        (__attribute__((address_space(3))) void*)l,
        16, 0, 0);
}

// ---- half-tile staging (128 rows x 64 cols bf16 = 16KB, 2 loads/thread) ----
// A buffer layout is mh-major: LDS slot = mh*128 + wr*64 + (ii*16+lm), so the
// staged "half h" == exactly the rows read in phases with mh==h.
// chunk c: q=(c>>3)&63, row = ((c>>9)&1)*128 + h*64 + q  (wr-part from c>>9)
__device__ __forceinline__ void stage_half_A(const u16* Ag, size_t ld, int k2,
                                             int h, u16* Abuf, int tid) {
    #pragma unroll
    for (int it = 0; it < 2; ++it) {
        int c   = it * 512 + tid;          // 0..1023
        int q   = (c >> 3) & 63;
        int row = ((c >> 9) & 1) * 128 + h * 64 + q;
        int sc  = ((c & 7) ^ (q & 7)) << 3;
        gload16(Ag + (size_t)row * ld + k2 + sc, Abuf + h * 8192 + c * 8);
    }
}
// B buffer layout is plain [256][64] with XOR swizzle; half h = rows h*128..+127
__device__ __forceinline__ void stage_half_B(const u16* Bg, size_t ld, int k2,
                                             int h, u16* Bbuf, int tid) {
    #pragma unroll
    for (int it = 0; it < 2; ++it) {
        int c   = it * 512 + tid;          // 0..1023
        int r   = c >> 3;                  // 0..127
        int row = h * 128 + r;
        int sc  = ((c & 7) ^ (r & 7)) << 3;
        gload16(Bg + (size_t)row * ld + k2 + sc, Bbuf + h * 8192 + c * 8);
    }
}

// ---------------------------------------------------------------- cvt f32->bf16
__global__ __launch_bounds__(256) void cvt_kernel(const float* __restrict__ src,
                                                  u16* __restrict__ dst, long n) {
    long i0 = ((long)blockIdx.x * 256 + threadIdx.x) * 8;
    long stride = (long)gridDim.x * 256 * 8;
    for (long i = i0; i < n; i += stride) {
        float4 a = *(const float4*)(src + i);
        float4 b = *(const float4*)(src + i + 4);
        uint4 o;
        o.x = (uint32_t)f2bf(a.x) | ((uint32_t)f2bf(a.y) << 16);
        o.y = (uint32_t)f2bf(a.z) | ((uint32_t)f2bf(a.w) << 16);
        o.z = (uint32_t)f2bf(b.x) | ((uint32_t)f2bf(b.y) << 16);
        o.w = (uint32_t)f2bf(b.z) | ((uint32_t)f2bf(b.w) << 16);
        *(uint4*)(dst + i) = o;
    }
}

// ---------------------------------------------------------------- cvt+interleave w1/w3
__global__ __launch_bounds__(256) void cvt13_kernel(const float* __restrict__ w1,
                                                    const float* __restrict__ w3,
                                                    u16* __restrict__ dst) {
    const int r  = blockIdx.x;            // 0 .. 8*2816-1
    const int e  = r / NPRIME;
    const int np = r - e * NPRIME;
    const int p  = np >> 5;
    const int s  = (np >> 4) & 1;
    const int c  = np & 15;
    const int hcol = p * 16 + c;
    const float* src = (s ? w3 : w1) + ((size_t)e * HIDDEN + hcol) * DIM;
    u16* d = dst + (size_t)r * DIM;
    const int i = threadIdx.x * 8;
    float4 a = *(const float4*)(src + i);
    float4 b = *(const float4*)(src + i + 4);
    uint4 o;
    o.x = (uint32_t)f2bf(a.x) | ((uint32_t)f2bf(a.y) << 16);
    o.y = (uint32_t)f2bf(a.z) | ((uint32_t)f2bf(a.w) << 16);
    o.z = (uint32_t)f2bf(b.x) | ((uint32_t)f2bf(b.y) << 16);
    o.w = (uint32_t)f2bf(b.z) | ((uint32_t)f2bf(b.w) << 16);
    *(uint4*)(d + i) = o;
}

// ======================= 256x256 8-phase GEMM core (m201 port) ==============
// BM=BN=256, BK=64, 512 thr = 8 waves (2M x 4N), wave tile 128x64.
// 2-deep LDS double buffer; 4 phases per K-tile, one half-tile staged per
// phase; counted vmcnt(4) once per K-tile. Stage schedule (tile t):
//   p0: read A(mh0,k0)+B(k0), stage A1(t+1)   [clobbers A1(t-1), read t-1 p3]
//   p1: read A(mh0,k1)+B(k1), stage B1(t+1)   [clobbers B1(t-1), read t-1 p1]
//   p2: read A(mh1,k0),       stage A0(t+2)   [clobbers A0(t),   read t  p1]
//   p3: read A(mh1,k1),       stage B0(t+2)   [clobbers B0(t),   read t  p1]
// Each clobbered region's last reads complete before the stage's phase starts
// (double barrier + lgkmcnt(0) per phase) -> race-free by construction.
// Boundary vmcnt(4) leaves exactly {A0(t+2),B0(t+2)} in flight and proves all
// of tile t+1 landed.

#define PHASE_TAIL(MH, BK_REGS)                                                 \
    __builtin_amdgcn_s_barrier();                                               \
    asm volatile("s_waitcnt lgkmcnt(0)" ::: "memory");                          \
    __builtin_amdgcn_s_setprio(1);                                              \
    _Pragma("unroll")                                                           \
    for (int ii = 0; ii < 4; ++ii)                                              \
        _Pragma("unroll")                                                       \
        for (int j = 0; j < 4; ++j)                                             \
            acc[MH * 4 + ii][j] = __builtin_amdgcn_mfma_f32_16x16x32_bf16(      \
                af[ii], BK_REGS[j], acc[MH * 4 + ii][j], 0, 0, 0);              \
    __builtin_amdgcn_s_setprio(0);

#define GCORE(LD, NT)                                                           \
    const int tid  = threadIdx.x;                                               \
    const int lane = tid & 63;                                                  \
    const int wid  = tid >> 6;                                                  \
    const int wr   = wid >> 2;     /* 0..1 -> 128-row group */                  \
    const int wc   = wid & 3;      /* 0..3 -> 64-col group  */                  \
    const int lq   = lane >> 4;                                                 \
    const int lm   = lane & 15;                                                 \
    const int xk   = lm & 7;                                                    \
    f32x4 acc[8][4] = {};                                                       \
    stage_half_A(Ag, LD, 0, 0, As[0], tid);                                     \
    stage_half_B(Bg, LD, 0, 0, Bs[0], tid);                                     \
    stage_half_A(Ag, LD, 0, 1, As[0], tid);                                     \
    stage_half_B(Bg, LD, 0, 1, Bs[0], tid);                                     \
    stage_half_A(Ag, LD, 64, 0, As[1], tid);                                    \
    stage_half_B(Bg, LD, 64, 0, Bs[1], tid);                                    \
    asm volatile("s_waitcnt vmcnt(4)" ::: "memory");                            \
    __builtin_amdgcn_s_barrier();                                               \
    for (int t = 0; t < NT; ++t) {                                              \
        const u16* Ap = As[t & 1];                                              \
        const u16* Bp = Bs[t & 1];                                              \
        short8 af[4], bk0[4], bk1[4];                                           \
        /* phase 0 */                                                           \
        _Pragma("unroll")                                                       \
        for (int ii = 0; ii < 4; ++ii)                                          \
            af[ii] = *(const short8*)&Ap[(wr * 64 + ii * 16 + lm) * 64 + ((lq ^ xk) << 3)]; \
        _Pragma("unroll")                                                       \
        for (int j = 0; j < 4; ++j)                                             \
            bk0[j] = *(const short8*)&Bp[(wc * 64 + j * 16 + lm) * 64 + ((lq ^ xk) << 3)]; \
        if (t + 1 < NT) stage_half_A(Ag, LD, (t + 1) * 64, 1, As[(t + 1) & 1], tid); \
        PHASE_TAIL(0, bk0)                                                      \
        __builtin_amdgcn_s_barrier();                                           \
        /* phase 1 */                                                           \
        _Pragma("unroll")                                                       \
        for (int ii = 0; ii < 4; ++ii)                                          \
            af[ii] = *(const short8*)&Ap[(wr * 64 + ii * 16 + lm) * 64 + (((4 + lq) ^ xk) << 3)]; \
        _Pragma("unroll")                                                       \
        for (int j = 0; j < 4; ++j)                                             \
            bk1[j] = *(const short8*)&Bp[(wc * 64 + j * 16 + lm) * 64 + (((4 + lq) ^ xk) << 3)]; \
        if (t + 1 < NT) stage_half_B(Bg, LD, (t + 1) * 64, 1, Bs[(t + 1) & 1], tid); \
        PHASE_TAIL(0, bk1)                                                      \
        __builtin_amdgcn_s_barrier();                                           \
        /* phase 2 */                                                           \
        _Pragma("unroll")                                                       \
        for (int ii = 0; ii < 4; ++ii)                                          \
            af[ii] = *(const short8*)&Ap[(128 + wr * 64 + ii * 16 + lm) * 64 + ((lq ^ xk) << 3)]; \
        if (t + 2 < NT) stage_half_A(Ag, LD, (t + 2) * 64, 0, As[t & 1], tid);  \
        PHASE_TAIL(1, bk0)                                                      \
        __builtin_amdgcn_s_barrier();                                           \
        /* phase 3 */                                                           \
        _Pragma("unroll")                                                       \
        for (int ii = 0; ii < 4; ++ii)                                          \
            af[ii] = *(const short8*)&Ap[(128 + wr * 64 + ii * 16 + lm) * 64 + (((4 + lq) ^ xk) << 3)]; \
        if (t + 2 < NT) stage_half_B(Bg, LD, (t + 2) * 64, 0, Bs[t & 1], tid);  \
        PHASE_TAIL(1, bk1)                                                      \
        if (t + 2 < NT) { asm volatile("s_waitcnt vmcnt(4)" ::: "memory"); }    \
        else            { asm volatile("s_waitcnt vmcnt(0)" ::: "memory"); }    \
        __builtin_amdgcn_s_barrier();                                           \
    }

// ---------------------------------------------------------------- FFN1 (X @ B'^T, fused SwiGLU)
__global__ __launch_bounds__(512, 2) void ffn1_kernel(
    const u16* __restrict__ xb, const u16* __restrict__ wb13,
    const int* __restrict__ ntpe, u16* __restrict__ hb)
{
    __shared__ __align__(16) u16 As[2][16384];
    __shared__ __align__(16) u16 Bs[2][16384];

    const int nwg = 8 * 11 * NEXP;   // 704, %8==0
    int logical = (blockIdx.x & 7) * (nwg >> 3) + (blockIdx.x >> 3);
    const int mt = logical & 7;
    int rest = logical >> 3;
    const int nt = rest % 11;
    const int e  = rest / 11;

    int base = 0;
    #pragma unroll
    for (int i = 0; i < NEXP; ++i) base += (i < e) ? ntpe[i] : 0;
    const int cnt = ntpe[e];
    if (mt * 256 >= cnt) return;   // block-uniform

    const size_t m0 = (size_t)base + (size_t)mt * 256;
    const u16* Ag = xb   + m0 * DIM;
    const u16* Bg = wb13 + ((size_t)e * NPRIME + nt * 256) * DIM;

    GCORE(DIM, 32)

    // epilogue: within each 64-col wave group, frag j even = c1, j odd = c3
    // (same 16 hidden cols). C/D map: col=lane&15, row=(lane>>4)*4+r.
    #pragma unroll
    for (int i = 0; i < 8; ++i)
        #pragma unroll
        for (int jp = 0; jp < 4; jp += 2) {
            const int p16 = nt * 8 + wc * 2 + (jp >> 1);
            #pragma unroll
            for (int r = 0; r < 4; ++r) {
                int mrow = mt * 256 + wr * 128 + i * 16 + lq * 4 + r;
                if (mrow < cnt) {
                    float v1 = acc[i][jp][r];
                    float v3 = acc[i][jp + 1][r];
                    float h = (v1 / (1.f + __expf(-v1))) * v3;
                    hb[((size_t)base + mrow) * HIDDEN + p16 * 16 + lm] = f2bf(h);
                }
            }
        }
}

// ---------------------------------------------------------------- FFN2 (h @ W2^T -> out fp32)
__global__ __launch_bounds__(512, 2) void ffn2_kernel(
    const u16* __restrict__ hb, const u16* __restrict__ w2b,
    const int* __restrict__ ntpe, float* __restrict__ out)
{
    __shared__ __align__(16) u16 As[2][16384];
    __shared__ __align__(16) u16 Bs[2][16384];

    const int nwg = 8 * 8 * NEXP;   // 512, %8==0
    int logical = (blockIdx.x & 7) * (nwg >> 3) + (blockIdx.x >> 3);
    const int mt = logical & 7;
    int rest = logical >> 3;
    const int nt = rest % 8;
    const int e  = rest / 8;

    int base = 0;
    #pragma unroll
    for (int i = 0; i < NEXP; ++i) base += (i < e) ? ntpe[i] : 0;
    const int cnt = ntpe[e];
    if (mt * 256 >= cnt) return;

    const size_t m0 = (size_t)base + (size_t)mt * 256;
    const u16* Ag = hb  + m0 * HIDDEN;
    const u16* Bg = w2b + ((size_t)e * DIM + nt * 256) * HIDDEN;

    GCORE(HIDDEN, 22)

    #pragma unroll
    for (int i = 0; i < 8; ++i)
        #pragma unroll
        for (int j = 0; j < 4; ++j)
            #pragma unroll
            for (int r = 0; r < 4; ++r) {
                int mrow = mt * 256 + wr * 128 + i * 16 + lq * 4 + r;
                if (mrow < cnt)
                    out[((size_t)base + mrow) * DIM + (nt * 256 + wc * 64 + j * 16 + lm)] = acc[i][j][r];
            }
}

// ---------------------------------------------------------------- launch
extern "C" void kernel_launch(void* const* d_in, const int* in_sizes, int n_in,
                              void* d_out, int out_size, void* d_ws, size_t ws_size,
                              hipStream_t stream) {
    const float* x  = (const float*)d_in[0];
    const float* w1 = (const float*)d_in[1];
    const float* w2 = (const float*)d_in[2];  // dict order: x, w1, w2, w3, ntpe
    const float* w3 = (const float*)d_in[3];
    const int* ntpe = (const int*)d_in[4];
    float* out = (float*)d_out;

    u16* xb   = (u16*)d_ws;
    u16* wb13 = xb   + (size_t)NTOK * DIM;
    u16* w2b  = wb13 + (size_t)NEXP * NPRIME * DIM;
    u16* hb   = w2b  + (size_t)NEXP * DIM * HIDDEN;

    cvt_kernel<<<2048, 256, 0, stream>>>(x,  xb,  (long)NTOK * DIM);
    cvt_kernel<<<2048, 256, 0, stream>>>(w2, w2b, (long)NEXP * DIM * HIDDEN);
    cvt13_kernel<<<NEXP * NPRIME, 256, 0, stream>>>(w1, w3, wb13);

    ffn1_kernel<<<8 * 11 * NEXP, 512, 0, stream>>>(xb, wb13, ntpe, hb);
    ffn2_kernel<<<8 * 8 * NEXP, 512, 0, stream>>>(hb, w2b, ntpe, out);
}

// Round 5
// 452.239 us; speedup vs baseline: 1.2073x; 1.2073x over previous
//
#include <hip/hip_runtime.h>
#include <stdint.h>

#define NTOK 16384
#define DIM 2048
#define HIDDEN 1408
#define NEXP 8
#define NPRIME 2816   // 2*HIDDEN, 16-col interleaved w1/w3

typedef short short8 __attribute__((ext_vector_type(8)));
typedef float f32x4 __attribute__((ext_vector_type(4)));
typedef unsigned short u16;

// round-to-nearest-even fp32 -> bf16 (inputs finite; no NaN handling needed)
__device__ __forceinline__ u16 f2bf(float f) {
    uint32_t u = __float_as_uint(f);
    return (u16)((u + 0x7fffu + ((u >> 16) & 1u)) >> 16);
}

// async global->LDS, 16B per lane. LDS dest is wave-uniform base + lane*16.
__device__ __forceinline__ void gload16(const u16* g, u16* l) {
    __builtin_amdgcn_global_load_lds(
        (const __attribute__((address_space(1))) void*)g,
        (__attribute__((address_space(3))) void*)l,
        16, 0, 0);
}

// ---------------------------------------------------------------- cvt f32->bf16
__global__ __launch_bounds__(256) void cvt_kernel(const float* __restrict__ src,
                                                  u16* __restrict__ dst, long n) {
    long i0 = ((long)blockIdx.x * 256 + threadIdx.x) * 8;
    long stride = (long)gridDim.x * 256 * 8;
    for (long i = i0; i < n; i += stride) {
        float4 a = *(const float4*)(src + i);
        float4 b = *(const float4*)(src + i + 4);
        uint4 o;
        o.x = (uint32_t)f2bf(a.x) | ((uint32_t)f2bf(a.y) << 16);
        o.y = (uint32_t)f2bf(a.z) | ((uint32_t)f2bf(a.w) << 16);
        o.z = (uint32_t)f2bf(b.x) | ((uint32_t)f2bf(b.y) << 16);
        o.w = (uint32_t)f2bf(b.z) | ((uint32_t)f2bf(b.w) << 16);
        *(uint4*)(dst + i) = o;
    }
}

// ---------------------------------------------------------------- cvt+interleave w1/w3
// dst row n' (of 2816 per expert): p=n'>>5, s=(n'>>4)&1, c=n'&15; hidden col = p*16+c
__global__ __launch_bounds__(256) void cvt13_kernel(const float* __restrict__ w1,
                                                    const float* __restrict__ w3,
                                                    u16* __restrict__ dst) {
    const int r  = blockIdx.x;            // 0 .. 8*2816-1
    const int e  = r / NPRIME;
    const int np = r - e * NPRIME;
    const int p  = np >> 5;
    const int s  = (np >> 4) & 1;
    const int c  = np & 15;
    const int hcol = p * 16 + c;
    const float* src = (s ? w3 : w1) + ((size_t)e * HIDDEN + hcol) * DIM;
    u16* d = dst + (size_t)r * DIM;
    const int i = threadIdx.x * 8;
    float4 a = *(const float4*)(src + i);
    float4 b = *(const float4*)(src + i + 4);
    uint4 o;
    o.x = (uint32_t)f2bf(a.x) | ((uint32_t)f2bf(a.y) << 16);
    o.y = (uint32_t)f2bf(a.z) | ((uint32_t)f2bf(a.w) << 16);
    o.z = (uint32_t)f2bf(b.x) | ((uint32_t)f2bf(b.y) << 16);
    o.w = (uint32_t)f2bf(b.z) | ((uint32_t)f2bf(b.w) << 16);
    *(uint4*)(d + i) = o;
}

// ---------------------------------------------------------------- FFN1 (X @ B'^T, fused SwiGLU)
// m97 structure: 128x128 tile, BK=64, 256 threads = 4 waves (2x2), wave 64x64.
// 5 blocks/CU (32KB LDS) -> inter-block overlap hides the barrier drain.
__global__ __launch_bounds__(256) void ffn1_kernel(
    const u16* __restrict__ xb, const u16* __restrict__ wb13,
    const int* __restrict__ ntpe, u16* __restrict__ hb)
{
    __shared__ u16 As[128 * 64];
    __shared__ u16 Bs[128 * 64];

    // XCD swizzle: nwg=2816 (%8==0), chunk 352 = one expert (22 nt x 16 mt),
    // mt fastest -> B-panel reused by 16 consecutive blocks on one XCD.
    const int nwg = 16 * 22 * NEXP;
    int logical = (blockIdx.x & 7) * (nwg >> 3) + (blockIdx.x >> 3);
    const int mt = logical & 15;
    int rest = logical >> 4;
    const int nt = rest % 22;
    const int e  = rest / 22;

    int base = 0;
    #pragma unroll
    for (int i = 0; i < NEXP; ++i) base += (i < e) ? ntpe[i] : 0;
    const int cnt = ntpe[e];
    if (mt * 128 >= cnt) return;

    const int tid  = threadIdx.x;
    const int lane = tid & 63;
    const int wid  = tid >> 6;   // 0..3
    const int wr   = wid >> 1;   // 0..1 -> 64-row group
    const int wc   = wid & 1;    // 0..1 -> 64-col group
    const int lq   = lane >> 4;
    const int lm   = lane & 15;

    const size_t m0 = (size_t)base + (size_t)mt * 128;
    const u16* Ag = xb   + m0 * DIM;
    const u16* Bg = wb13 + ((size_t)e * NPRIME + nt * 128) * DIM;

    f32x4 acc[4][4] = {};

    for (int k0 = 0; k0 < DIM; k0 += 64) {
        if (k0) __syncthreads();
        #pragma unroll
        for (int it = 0; it < 4; ++it) {
            int c   = it * 256 + tid;            // 0..1023
            int row = c >> 3;                    // 0..127
            int col = ((c & 7) ^ (row & 7)) * 8; // swizzled 8-elem chunk
            size_t go = (size_t)row * DIM + k0 + col;
            gload16(Ag + go, &As[c * 8]);
            gload16(Bg + go, &Bs[c * 8]);
        }
        __syncthreads();

        #pragma unroll
        for (int kk = 0; kk < 2; ++kk) {
            const int gc = kk * 4 + lq;
            short8 af[4], bf[4];
            #pragma unroll
            for (int i = 0; i < 4; ++i) {
                int ar = wr * 64 + i * 16 + lm;
                af[i] = *(const short8*)&As[ar * 64 + ((gc ^ (ar & 7)) << 3)];
                int br = wc * 64 + i * 16 + lm;
                bf[i] = *(const short8*)&Bs[br * 64 + ((gc ^ (br & 7)) << 3)];
            }
            #pragma unroll
            for (int i = 0; i < 4; ++i)
                #pragma unroll
                for (int j = 0; j < 4; ++j)
                    acc[i][j] = __builtin_amdgcn_mfma_f32_16x16x32_bf16(af[i], bf[j], acc[i][j], 0, 0, 0);
        }
    }

    // epilogue: frag j even = c1, j odd = c3 (same 16 hidden cols).
    // h = silu(c1)*c3.  C/D map: col=lane&15, row=(lane>>4)*4+r.
    #pragma unroll
    for (int i = 0; i < 4; ++i)
        #pragma unroll
        for (int jp = 0; jp < 4; jp += 2) {
            const int p = nt * 4 + wc * 2 + (jp >> 1);   // 16-col hidden group
            #pragma unroll
            for (int r = 0; r < 4; ++r) {
                int mrow = mt * 128 + wr * 64 + i * 16 + lq * 4 + r;
                if (mrow < cnt) {
                    float v1 = acc[i][jp][r];
                    float v3 = acc[i][jp + 1][r];
                    float h = (v1 / (1.f + __expf(-v1))) * v3;
                    hb[((size_t)base + mrow) * HIDDEN + p * 16 + lm] = f2bf(h);
                }
            }
        }
}

// ---------------------------------------------------------------- FFN2 (h @ W2^T -> out fp32)
__global__ __launch_bounds__(256) void ffn2_kernel(
    const u16* __restrict__ hb, const u16* __restrict__ w2b,
    const int* __restrict__ ntpe, float* __restrict__ out)
{
    __shared__ u16 As[128 * 64];
    __shared__ u16 Bs[128 * 64];

    // XCD swizzle: nwg=2048 (%8==0), chunk 256 = one expert (16 nt x 16 mt).
    int logical = (blockIdx.x & 7) * 256 + (blockIdx.x >> 3);
    const int mt = logical & 15;
    int rest = logical >> 4;
    const int nt = rest & 15;
    const int e  = rest >> 4;

    int base = 0;
    #pragma unroll
    for (int i = 0; i < NEXP; ++i) base += (i < e) ? ntpe[i] : 0;
    const int cnt = ntpe[e];
    if (mt * 128 >= cnt) return;

    const int tid  = threadIdx.x;
    const int lane = tid & 63;
    const int wid  = tid >> 6;   // 0..3
    const int wr   = wid >> 1;   // 0..1 -> 64-row group
    const int wc   = wid & 1;    // 0..1 -> 64-col group
    const int lq   = lane >> 4;
    const int lm   = lane & 15;

    const size_t m0 = (size_t)base + (size_t)mt * 128;
    const int    n0 = nt * 128;
    const u16* Ag = hb  + m0 * HIDDEN;
    const u16* Bg = w2b + ((size_t)e * DIM + n0) * HIDDEN;

    f32x4 acc[4][4] = {};

    for (int k0 = 0; k0 < HIDDEN; k0 += 64) {
        if (k0) __syncthreads();
        #pragma unroll
        for (int it = 0; it < 4; ++it) {
            int c   = it * 256 + tid;
            int row = c >> 3;
            int col = ((c & 7) ^ (row & 7)) * 8;
            size_t go = (size_t)row * HIDDEN + k0 + col;
            gload16(Ag + go, &As[c * 8]);
            gload16(Bg + go, &Bs[c * 8]);
        }
        __syncthreads();

        #pragma unroll
        for (int kk = 0; kk < 2; ++kk) {
            const int gc = kk * 4 + lq;
            short8 af[4], bf[4];
            #pragma unroll
            for (int i = 0; i < 4; ++i) {
                int ar = wr * 64 + i * 16 + lm;
                af[i] = *(const short8*)&As[ar * 64 + ((gc ^ (ar & 7)) << 3)];
                int br = wc * 64 + i * 16 + lm;
                bf[i] = *(const short8*)&Bs[br * 64 + ((gc ^ (br & 7)) << 3)];
            }
            #pragma unroll
            for (int i = 0; i < 4; ++i)
                #pragma unroll
                for (int j = 0; j < 4; ++j)
                    acc[i][j] = __builtin_amdgcn_mfma_f32_16x16x32_bf16(af[i], bf[j], acc[i][j], 0, 0, 0);
        }
    }

    #pragma unroll
    for (int i = 0; i < 4; ++i)
        #pragma unroll
        for (int j = 0; j < 4; ++j)
            #pragma unroll
            for (int r = 0; r < 4; ++r) {
                int mrow = mt * 128 + wr * 64 + i * 16 + lq * 4 + r;
                if (mrow < cnt)
                    out[((size_t)base + mrow) * DIM + (n0 + wc * 64 + j * 16 + lm)] = acc[i][j][r];
            }
}

// ---------------------------------------------------------------- launch
extern "C" void kernel_launch(void* const* d_in, const int* in_sizes, int n_in,
                              void* d_out, int out_size, void* d_ws, size_t ws_size,
                              hipStream_t stream) {
    const float* x  = (const float*)d_in[0];
    const float* w1 = (const float*)d_in[1];
    const float* w2 = (const float*)d_in[2];  // dict order: x, w1, w2, w3, ntpe
    const float* w3 = (const float*)d_in[3];
    const int* ntpe = (const int*)d_in[4];
    float* out = (float*)d_out;

    // ws layout (bf16): xb | wb13 (interleaved w1/w3) | w2b | hb
    u16* xb   = (u16*)d_ws;
    u16* wb13 = xb   + (size_t)NTOK * DIM;
    u16* w2b  = wb13 + (size_t)NEXP * NPRIME * DIM;
    u16* hb   = w2b  + (size_t)NEXP * DIM * HIDDEN;

    // order: w2 first, then x, then w13 -> ffn1's inputs are most L3-warm
    cvt_kernel<<<2048, 256, 0, stream>>>(w2, w2b, (long)NEXP * DIM * HIDDEN);
    cvt_kernel<<<2048, 256, 0, stream>>>(x,  xb,  (long)NTOK * DIM);
    cvt13_kernel<<<NEXP * NPRIME, 256, 0, stream>>>(w1, w3, wb13);

    ffn1_kernel<<<16 * 22 * NEXP, 256, 0, stream>>>(xb, wb13, ntpe, hb);
    ffn2_kernel<<<16 * 16 * NEXP, 256, 0, stream>>>(hb, w2b, ntpe, out);
}